// Round 10
// baseline (103.304 us; speedup 1.0000x reference)
//
#include <hip/hip_runtime.h>

// SignatureScoringLoss — round 10: ILP x2, two pairs per wave.
//
// 272 blocks x 1 wave; each wave runs TWO independent signature-kernel pairs
// interleaved (Gram + PDE). With one wave per SIMD the PDE's 16-FMA dependent
// chain left ~50% issue gaps (VALUBusy evidence, r5-r9); the second pair's
// independent chain fills them.
// Mm storage per pair: 64 rows x 66 { [0][64 real][0] }; PDE read addr
// 65I+D+1 (stride 65 = 1 mod 32, conflict-free), ramp-in idx clamped to the
// per-row zero slot, ramp-out reads hit other rows' data but feed only
// virtual tiles whose outputs provably never reach a real tile (r9 argument).
// Max addr 65*63+127 = 4222 < 4224: in bounds. Weights (r2/r3-calibrated):
// XX 1/480 upper-triangle, XY -1/32.

#define SEQ   65
#define DIMS  8
#define MPOP  16
#define NBATCH 4
#define NPAIR_XX 120
#define NPAIRS (NBATCH*(NPAIR_XX + MPOP))   // 544
#define NBLK   (NPAIRS/2)                    // 272

__device__ __forceinline__ float wave_shr1(float x) {   // lane I <- I-1
    int xi = __builtin_bit_cast(int, x);
    int r  = __builtin_amdgcn_update_dpp(xi, xi, 0x138, 0xF, 0xF, false);
    return __builtin_bit_cast(float, r);
}
__device__ __forceinline__ float wave_shl1(float x) {   // lane I <- I+1
    int xi = __builtin_bit_cast(int, x);
    int r  = __builtin_amdgcn_update_dpp(xi, xi, 0x130, 0xF, 0xF, false);
    return __builtin_bit_cast(float, r);
}
__device__ __forceinline__ float ldm(const float* base, int idx) {
    return base[idx < 0 ? 0 : idx];          // clamp ramp-in to row's zero slot
}

struct PS { float l0,l1,l2,l3,b0,b1,b2,b3,cn; };

__device__ __forceinline__ void pde_step(PS& s, float m, bool lane0) {
    float t0 = wave_shr1(s.b0);
    float t1 = wave_shr1(s.b1);
    float t2 = wave_shr1(s.b2);
    float t3 = wave_shr1(s.b3);
    if (lane0) { t0 = 1.f; t1 = 1.f; t2 = 1.f; t3 = 1.f; }
    float c = s.cn; s.cn = t3;
    float q12 = m * m * (1.0f / 12.0f);
    float a   = 1.0f + 0.5f * m + q12;
    float nb  = q12 - 1.0f;
    float u0 = a*t0 + nb*c;
    float u1 = a*t1 + nb*t0;
    float u2 = a*t2 + nb*t1;
    float u3 = a*t3 + nb*t2;
    float q1 = a*s.l0 + u0;
    float q2 = a*q1 + u1;
    float q3 = a*q2 + u2;
    float q4 = a*q3 + u3;
    u0 = a*q1 + nb*s.l0; u1 = a*q2 + nb*q1; u2 = a*q3 + nb*q2; u3 = a*q4 + nb*q3;
    float r1 = a*s.l1 + u0;
    float r2 = a*r1 + u1;
    float r3 = a*r2 + u2;
    float r4 = a*r3 + u3;
    u0 = a*r1 + nb*s.l1; u1 = a*r2 + nb*r1; u2 = a*r3 + nb*r2; u3 = a*r4 + nb*r3;
    float w1 = a*s.l2 + u0;
    float w2 = a*w1 + u1;
    float w3 = a*w2 + u2;
    float w4 = a*w3 + u3;
    u0 = a*w1 + nb*s.l2; u1 = a*w2 + nb*w1; u2 = a*w3 + nb*w2; u3 = a*w4 + nb*w3;
    float v1 = a*s.l3 + u0;
    float v2 = a*v1 + u1;
    float v3 = a*v2 + u2;
    float v4 = a*v3 + u3;
    s.b0=v1; s.b1=v2; s.b2=v3; s.b3=v4;
    s.l0=q4; s.l1=r4; s.l2=w4; s.l3=v4;
}

__device__ __forceinline__ void decode_pair(int p, int& b, int& ii, int& jj,
                                            bool& cross) {
    if (p < NBATCH * NPAIR_XX) {
        b = p / NPAIR_XX;
        int q = p % NPAIR_XX;
        int i = 0, acc = 0;
        while (q >= acc + (MPOP - 1 - i)) { acc += (MPOP - 1 - i); ++i; }
        ii = i; jj = i + 1 + (q - acc); cross = false;
    } else {
        int t = p - NBATCH * NPAIR_XX;
        b = t / MPOP; ii = t % MPOP; jj = 0; cross = true;
    }
}

__global__ __launch_bounds__(64, 1) void sigker_kernel(
    const float* __restrict__ gen,    // (B,16,8,65)
    const float* __restrict__ realp,  // (B,8,65)
    float* __restrict__ ws)           // 544 partials
{
    __shared__ __align__(16) float YsA[SEQ * DIMS], YsB[SEQ * DIMS];
    __shared__ float YnA[SEQ], YnB[SEQ], R64A[SEQ], R64B[SEQ];
    __shared__ float MmA[64 * 66], MmB[64 * 66];

    const int tid = threadIdx.x;      // one wave
    const int I   = tid;
    const bool lane0 = (I == 0);
    const int bid = blockIdx.x;
    const int pA = 2 * bid, pB = 2 * bid + 1;

    int bA_, iA, jA; bool crA;  decode_pair(pA, bA_, iA, jA, crA);
    int bB_, iB, jB; bool crB;  decode_pair(pB, bB_, iB, jB, crB);

    const float* XgA = gen + (size_t)(bA_ * MPOP + iA) * (DIMS * SEQ);
    const float* YgA = crA ? (realp + (size_t)bA_ * (DIMS * SEQ))
                           : (gen + (size_t)(bA_ * MPOP + jA) * (DIMS * SEQ));
    const float* XgB = gen + (size_t)(bB_ * MPOP + iB) * (DIMS * SEQ);
    const float* YgB = crB ? (realp + (size_t)bB_ * (DIMS * SEQ))
                           : (gen + (size_t)(bB_ * MPOP + jB) * (DIMS * SEQ));

    // ---- zero own-row boundary slots; stage y paths ----
    MmA[66 * I] = 0.f;  MmA[66 * I + 65] = 0.f;
    MmB[66 * I] = 0.f;  MmB[66 * I + 65] = 0.f;
    for (int f = tid; f < SEQ * DIMS; f += 64) {
        int d = f / SEQ, s = f - d * SEQ;
        YsA[s * DIMS + d] = YgA[f];
        YsB[s * DIMS + d] = YgB[f];
    }
    float xA[DIMS], x64A[DIMS], xB[DIMS], x64B[DIMS];
    float xnA = 0.f, xn64A = 0.f, xnB = 0.f, xn64B = 0.f;
    #pragma unroll
    for (int d = 0; d < DIMS; ++d) {
        xA[d]   = XgA[d * SEQ + I];    xnA   += xA[d] * xA[d];
        x64A[d] = XgA[d * SEQ + 64];   xn64A += x64A[d] * x64A[d];
        xB[d]   = XgB[d * SEQ + I];    xnB   += xB[d] * xB[d];
        x64B[d] = XgB[d * SEQ + 64];   xn64B += x64B[d] * x64B[d];
    }
    __syncthreads();

    // ---- pre-pass: |y_t|^2 and x_64 e-rows, both pairs ----
    for (int t = tid; t < SEQ; t += 64) {
        const float4* yv = (const float4*)&YsA[t * DIMS];
        float4 ya = yv[0], yb = yv[1];
        float yn  = ya.x*ya.x + ya.y*ya.y + ya.z*ya.z + ya.w*ya.w
                  + yb.x*yb.x + yb.y*yb.y + yb.z*yb.z + yb.w*yb.w;
        float dot = x64A[0]*ya.x + x64A[1]*ya.y + x64A[2]*ya.z + x64A[3]*ya.w
                  + x64A[4]*yb.x + x64A[5]*yb.y + x64A[6]*yb.z + x64A[7]*yb.w;
        YnA[t] = yn;
        R64A[t] = __expf(2.f*dot - xn64A - yn);
        const float4* zv = (const float4*)&YsB[t * DIMS];
        float4 za = zv[0], zb = zv[1];
        float zn  = za.x*za.x + za.y*za.y + za.z*za.z + za.w*za.w
                  + zb.x*zb.x + zb.y*zb.y + zb.z*zb.z + zb.w*zb.w;
        float dtB = x64B[0]*za.x + x64B[1]*za.y + x64B[2]*za.z + x64B[3]*za.w
                  + x64B[4]*zb.x + x64B[5]*zb.y + x64B[6]*zb.z + x64B[7]*zb.w;
        YnB[t] = zn;
        R64B[t] = __expf(2.f*dtB - xn64B - zn);
    }
    __syncthreads();

    // ---- Gram: lane I streams e_I(t) for both pairs; e_{I+1} via DPP ----
    float* mwA = &MmA[66 * I];        // real data at idx 1..64
    float* mwB = &MmB[66 * I];
    float epA, enpA, epB, enpB;
    {
        const float4* yv = (const float4*)&YsA[0];
        float4 ya = yv[0], yb = yv[1];
        float dA = xA[0]*ya.x + xA[1]*ya.y + xA[2]*ya.z + xA[3]*ya.w
                 + xA[4]*yb.x + xA[5]*yb.y + xA[6]*yb.z + xA[7]*yb.w;
        float eA = __expf(2.f*dA - xnA - YnA[0]);
        float enA = wave_shl1(eA);
        enA = (I == 63) ? R64A[0] : enA;
        epA = eA; enpA = enA;
        const float4* zv = (const float4*)&YsB[0];
        float4 za = zv[0], zb = zv[1];
        float dB = xB[0]*za.x + xB[1]*za.y + xB[2]*za.z + xB[3]*za.w
                 + xB[4]*zb.x + xB[5]*zb.y + xB[6]*zb.z + xB[7]*zb.w;
        float eB = __expf(2.f*dB - xnB - YnB[0]);
        float enB = wave_shl1(eB);
        enB = (I == 63) ? R64B[0] : enB;
        epB = eB; enpB = enB;
    }
    #pragma unroll 4
    for (int t = 1; t < SEQ; ++t) {
        const float4* yv = (const float4*)&YsA[t * DIMS];
        float4 ya = yv[0], yb = yv[1];
        float dA = xA[0]*ya.x + xA[1]*ya.y + xA[2]*ya.z + xA[3]*ya.w
                 + xA[4]*yb.x + xA[5]*yb.y + xA[6]*yb.z + xA[7]*yb.w;
        float eA = __expf(2.f*dA - xnA - YnA[t]);
        float enA = wave_shl1(eA);
        enA = (I == 63) ? R64A[t] : enA;
        mwA[t] = ((enA - enpA) + (epA - eA)) * (1.0f / 16.0f);
        epA = eA; enpA = enA;
        const float4* zv = (const float4*)&YsB[t * DIMS];
        float4 za = zv[0], zb = zv[1];
        float dB = xB[0]*za.x + xB[1]*za.y + xB[2]*za.z + xB[3]*za.w
                 + xB[4]*zb.x + xB[5]*zb.y + xB[6]*zb.z + xB[7]*zb.w;
        float eB = __expf(2.f*dB - xnB - YnB[t]);
        float enB = wave_shl1(eB);
        enB = (I == 63) ? R64B[t] : enB;
        mwB[t] = ((enB - enpB) + (epB - eB)) * (1.0f / 16.0f);
        epB = eB; enpB = enB;
    }
    // Mm row I written+read only by lane I (wave-ordered DS): no barrier.

    // ---- PDE: 127 steps, two interleaved pairs, 8-deep m prefetch ----
    PS SA = {1,1,1,1, 1,1,1,1, 1};
    PS SB = {1,1,1,1, 1,1,1,1, 1};
    const int ib = 1 - I;             // m idx for step D = ib + D (clamp at 0)
    const float* brA = &MmA[66 * I];
    const float* brB = &MmB[66 * I];

    float mA[8], mB[8];
    #pragma unroll
    for (int k = 0; k < 8; ++k) { mA[k] = ldm(brA, ib + k); mB[k] = ldm(brB, ib + k); }

    for (int g = 0; g < 14; ++g) {    // steps D = 8g .. 8g+7 (0..111)
        float nA[8], nB[8];
        const int D8 = g * 8 + 8;
        #pragma unroll
        for (int k = 0; k < 8; ++k) {
            nA[k] = ldm(brA, ib + D8 + k);
            nB[k] = ldm(brB, ib + D8 + k);
        }
        #pragma unroll
        for (int k = 0; k < 8; ++k) {
            pde_step(SA, mA[k], lane0);
            pde_step(SB, mB[k], lane0);
        }
        #pragma unroll
        for (int k = 0; k < 8; ++k) { mA[k] = nA[k]; mB[k] = nB[k]; }
    }
    // m holds D=112..119; load tail D=120..126 then run final 15 steps
    float eAt[7], eBt[7];
    #pragma unroll
    for (int k = 0; k < 7; ++k) {
        eAt[k] = ldm(brA, ib + 120 + k);
        eBt[k] = ldm(brB, ib + 120 + k);
    }
    #pragma unroll
    for (int k = 0; k < 8; ++k) { pde_step(SA, mA[k], lane0); pde_step(SB, mB[k], lane0); }
    #pragma unroll
    for (int k = 0; k < 7; ++k) { pde_step(SA, eAt[k], lane0); pde_step(SB, eBt[k], lane0); }

    if (tid == 63) {
        float wA = crA ? (-1.0f / 32.0f) : (1.0f / 480.0f);
        float wB = crB ? (-1.0f / 32.0f) : (1.0f / 480.0f);
        ws[pA] = wA * SA.b3;          // K[256][256] of pair A
        ws[pB] = wB * SB.b3;
    }
}

__global__ __launch_bounds__(64, 1) void sigker_reduce(
    const float* __restrict__ ws, float* __restrict__ out)
{
    const int lane = threadIdx.x;
    float s = 0.f;
    for (int k = lane; k < NPAIRS; k += 64) s += ws[k];
    #pragma unroll
    for (int off = 32; off >= 1; off >>= 1) s += __shfl_xor(s, off);
    if (lane == 0) out[0] = s;
}

extern "C" void kernel_launch(void* const* d_in, const int* in_sizes, int n_in,
                              void* d_out, int out_size, void* d_ws, size_t ws_size,
                              hipStream_t stream) {
    const float* gen   = (const float*)d_in[0];
    const float* realp = (const float*)d_in[1];
    if (n_in >= 2 && in_sizes[0] == NBATCH * DIMS * SEQ) {  // swapped order
        gen   = (const float*)d_in[1];
        realp = (const float*)d_in[0];
    }
    float* ws  = (float*)d_ws;
    float* out = (float*)d_out;
    sigker_kernel<<<NBLK, 64, 0, stream>>>(gen, realp, ws);
    sigker_reduce<<<1, 64, 0, stream>>>(ws, out);
}

// Round 11
// 91.718 us; speedup vs baseline: 1.1263x; 1.1263x over previous
//
#include <hip/hip_runtime.h>

// SignatureScoringLoss — round 11: single-pair waves (latency regime) with
// packed-FP32 math and fused final reduction.
//
// Evidence through r10: wall = one wave's single-pair cycle count (occupancy
// ~2.6%, excess SIMDs idle; 2-pairs-per-wave regressed). So: 544 blocks x
// 1 wave, minimize per-wave cycles.
//  - Mm compact layout 64x66 {[0][64 real][0]}: no zeroing pre-pass; ramp-in
//    m-loads clamp to the zero slot, ramp-out reads feed only virtual tiles
//    whose outputs provably never reach a real tile (r9/r10 argument).
//  - PDE u-terms and Gram dots as float2 ext-vectors -> v_pk_fma_f32.
//  - Final reduction fused via release/acquire (threadfence + atomic counter,
//    last block sums ws) — saves the second dispatch.
// Weights calibrated r2/r3: XX 1/480 (upper triangle), XY -1/32.

#define SEQ   65
#define DIMS  8
#define MPOP  16
#define NBATCH 4
#define NPAIR_XX 120
#define NPAIRS (NBATCH*(NPAIR_XX + MPOP))   // 544
#define MST 66

typedef float v2f __attribute__((ext_vector_type(2)));
static __device__ __forceinline__ v2f mk2(float x, float y) { return (v2f){x, y}; }

__device__ __forceinline__ float wave_shr1(float x) {   // lane I <- I-1
    int xi = __builtin_bit_cast(int, x);
    int r  = __builtin_amdgcn_update_dpp(xi, xi, 0x138, 0xF, 0xF, false);
    return __builtin_bit_cast(float, r);
}
__device__ __forceinline__ float wave_shl1(float x) {   // lane I <- I+1
    int xi = __builtin_bit_cast(int, x);
    int r  = __builtin_amdgcn_update_dpp(xi, xi, 0x130, 0xF, 0xF, false);
    return __builtin_bit_cast(float, r);
}
__device__ __forceinline__ float ldm(const float* base, int idx) {
    return base[idx < 0 ? 0 : idx];          // clamp ramp-in to row's zero slot
}

struct PS { float l0,l1,l2,l3,b0,b1,b2,b3,cn; };

__device__ __forceinline__ void pde_step(PS& s, float m, bool lane0) {
    float t0 = wave_shr1(s.b0);  t0 = lane0 ? 1.f : t0;
    float t1 = wave_shr1(s.b1);  t1 = lane0 ? 1.f : t1;
    float t2 = wave_shr1(s.b2);  t2 = lane0 ? 1.f : t2;
    float t3 = wave_shr1(s.b3);  t3 = lane0 ? 1.f : t3;
    float c = s.cn; s.cn = t3;
    float mm  = m * m;
    float q12 = mm * (1.0f / 12.0f);
    float a   = (1.0f + q12) + 0.5f * m;
    float nb  = q12 - 1.0f;
    v2f av = mk2(a, a), nv = mk2(nb, nb);
    // row 0: tops [c,t0..t3], left l0
    v2f u01 = av * mk2(t0, t1) + nv * mk2(c,  t0);
    v2f u23 = av * mk2(t2, t3) + nv * mk2(t1, t2);
    float q1 = a * s.l0 + u01.x;
    float q2 = a * q1   + u01.y;
    float q3 = a * q2   + u23.x;
    float q4 = a * q3   + u23.y;
    // row 1
    u01 = av * mk2(q1, q2) + nv * mk2(s.l0, q1);
    u23 = av * mk2(q3, q4) + nv * mk2(q2,  q3);
    float r1 = a * s.l1 + u01.x;
    float r2 = a * r1   + u01.y;
    float r3 = a * r2   + u23.x;
    float r4 = a * r3   + u23.y;
    // row 2
    u01 = av * mk2(r1, r2) + nv * mk2(s.l1, r1);
    u23 = av * mk2(r3, r4) + nv * mk2(r2,  r3);
    float w1 = a * s.l2 + u01.x;
    float w2 = a * w1   + u01.y;
    float w3 = a * w2   + u23.x;
    float w4 = a * w3   + u23.y;
    // row 3
    u01 = av * mk2(w1, w2) + nv * mk2(s.l2, w1);
    u23 = av * mk2(w3, w4) + nv * mk2(w2,  w3);
    float v1 = a * s.l3 + u01.x;
    float v2 = a * v1   + u01.y;
    float v3 = a * v2   + u23.x;
    float v4 = a * v3   + u23.y;
    s.b0=v1; s.b1=v2; s.b2=v3; s.b3=v4;
    s.l0=q4; s.l1=r4; s.l2=w4; s.l3=v4;
}

__global__ __launch_bounds__(64, 1) void sigker_kernel(
    const float* __restrict__ gen,    // (B,16,8,65)
    const float* __restrict__ realp,  // (B,8,65)
    float* __restrict__ ws,           // 544 partials
    unsigned* __restrict__ cnt,       // completion counter (pre-zeroed)
    float* __restrict__ out)
{
    __shared__ __align__(16) float YsF[SEQ * DIMS];   // y paths [s][d]
    __shared__ float YnL[SEQ];                        // |y_t|^2
    __shared__ float R64[SEQ];                        // e-row for x_64
    __shared__ float MmL[64 * MST];                   // {[0][64 real][0]} rows

    const int tid = threadIdx.x;      // one wave
    const int I   = tid;
    const bool lane0 = (I == 0);
    const int bid = blockIdx.x;

    // ---- decode pair (unordered XX upper triangle + XY) ----
    int b, ii, jj; bool cross;
    if (bid < NBATCH * NPAIR_XX) {
        b = bid / NPAIR_XX;
        int p = bid % NPAIR_XX;
        int i = 0, acc = 0;
        while (p >= acc + (MPOP - 1 - i)) { acc += (MPOP - 1 - i); ++i; }
        ii = i; jj = i + 1 + (p - acc); cross = false;
    } else {
        int t = bid - NBATCH * NPAIR_XX;
        b = t / MPOP; ii = t % MPOP; jj = 0; cross = true;
    }

    const float* Xg = gen + (size_t)(b * MPOP + ii) * (DIMS * SEQ);
    const float* Yg = cross ? (realp + (size_t)b * (DIMS * SEQ))
                            : (gen + (size_t)(b * MPOP + jj) * (DIMS * SEQ));

    // ---- zero own-row boundary slots; stage y; x_I & x_64 to regs ----
    MmL[MST * I] = 0.f;  MmL[MST * I + 65] = 0.f;
    for (int f = tid; f < SEQ * DIMS; f += 64) {
        int d = f / SEQ, s = f - d * SEQ;
        YsF[s * DIMS + d] = Yg[f];
    }
    v2f x01, x23, x45, x67, z01, z23, z45, z67;
    {
        float xv[DIMS], zv[DIMS];
        #pragma unroll
        for (int d = 0; d < DIMS; ++d) {
            xv[d] = Xg[d * SEQ + I];
            zv[d] = Xg[d * SEQ + 64];   // broadcast
        }
        x01 = mk2(xv[0],xv[1]); x23 = mk2(xv[2],xv[3]);
        x45 = mk2(xv[4],xv[5]); x67 = mk2(xv[6],xv[7]);
        z01 = mk2(zv[0],zv[1]); z23 = mk2(zv[2],zv[3]);
        z45 = mk2(zv[4],zv[5]); z67 = mk2(zv[6],zv[7]);
    }
    float xn0, xn64;
    {
        v2f sx = x01*x01 + x23*x23 + x45*x45 + x67*x67;
        v2f sz = z01*z01 + z23*z23 + z45*z45 + z67*z67;
        xn0 = sx.x + sx.y;  xn64 = sz.x + sz.y;
    }
    __syncthreads();

    // ---- pre-pass: |y_t|^2 and e-row for x_64 ----
    for (int t = tid; t < SEQ; t += 64) {
        const float4* yv = (const float4*)&YsF[t * DIMS];
        float4 ya = yv[0], yb = yv[1];
        v2f y01 = mk2(ya.x,ya.y), y23 = mk2(ya.z,ya.w);
        v2f y45 = mk2(yb.x,yb.y), y67 = mk2(yb.z,yb.w);
        v2f sn = y01*y01 + y23*y23 + y45*y45 + y67*y67;
        v2f sd = z01*y01 + z23*y23 + z45*y45 + z67*y67;
        float yn  = sn.x + sn.y;
        float dot = sd.x + sd.y;
        YnL[t] = yn;
        R64[t] = __expf(2.f*dot - xn64 - yn);
    }
    __syncthreads();

    // ---- Gram: lane I streams e_I(t); e_{I+1}(t) via DPP shl ----
    float* mrow = &MmL[MST * I];      // real data at idx 1..64
    float ep, enp;
    {
        const float4* yv = (const float4*)&YsF[0];
        float4 ya = yv[0], yb = yv[1];
        v2f sd = x01*mk2(ya.x,ya.y) + x23*mk2(ya.z,ya.w)
               + x45*mk2(yb.x,yb.y) + x67*mk2(yb.z,yb.w);
        float e  = __expf(2.f*(sd.x + sd.y) - xn0 - YnL[0]);
        float en = wave_shl1(e);
        en = (I == 63) ? R64[0] : en;
        ep = e; enp = en;
    }
    #pragma unroll 4
    for (int t = 1; t < SEQ; ++t) {
        const float4* yv = (const float4*)&YsF[t * DIMS];
        float4 ya = yv[0], yb = yv[1];
        v2f sd = x01*mk2(ya.x,ya.y) + x23*mk2(ya.z,ya.w)
               + x45*mk2(yb.x,yb.y) + x67*mk2(yb.z,yb.w);
        float e  = __expf(2.f*(sd.x + sd.y) - xn0 - YnL[t]);
        float en = wave_shl1(e);
        en = (I == 63) ? R64[t] : en;
        // inc[I][t-1] = G[I+1][t] + G[I][t-1] - G[I+1][t-1] - G[I][t]
        mrow[t] = ((en - enp) + (ep - e)) * (1.0f / 16.0f);
        ep = e; enp = en;
    }
    // mrow written+read only by lane I (wave-ordered DS): no barrier.

    // ---- PDE: 127 steps, 8-deep m prefetch ----
    PS S = {1,1,1,1, 1,1,1,1, 1};
    const int ib = 1 - I;             // m idx for step D = ib + D (clamp at 0)
    float m[8];
    #pragma unroll
    for (int k = 0; k < 8; ++k) m[k] = ldm(mrow, ib + k);

    for (int g = 0; g < 14; ++g) {    // steps D = 8g .. 8g+7  (0..111)
        float n[8];
        const int D8 = g * 8 + 8;
        #pragma unroll
        for (int k = 0; k < 8; ++k) n[k] = ldm(mrow, ib + D8 + k);
        #pragma unroll
        for (int k = 0; k < 8; ++k) pde_step(S, m[k], lane0);
        #pragma unroll
        for (int k = 0; k < 8; ++k) m[k] = n[k];
    }
    float mt[7];
    #pragma unroll
    for (int k = 0; k < 7; ++k) mt[k] = ldm(mrow, ib + 120 + k);
    #pragma unroll
    for (int k = 0; k < 8; ++k) pde_step(S, m[k], lane0);    // D=112..119
    #pragma unroll
    for (int k = 0; k < 7; ++k) pde_step(S, mt[k], lane0);   // D=120..126

    if (tid == 63) {
        float w = cross ? (-1.0f / 32.0f) : (1.0f / 480.0f);
        ws[bid] = w * S.b3;           // K[256][256]
    }

    // ---- fused final reduction (release/acquire, rocPRIM pattern) ----
    __threadfence();                  // release ws[bid] (same wave as store)
    unsigned old = 0;
    if (tid == 0) old = atomicAdd(cnt, 1u);
    old = __shfl(old, 0);
    if (old == NPAIRS - 1) {          // last block
        __threadfence();              // acquire
        float s = 0.f;
        for (int k = tid; k < NPAIRS; k += 64) s += ws[k];
        #pragma unroll
        for (int off = 32; off >= 1; off >>= 1) s += __shfl_xor(s, off);
        if (tid == 0) out[0] = s;
    }
}

extern "C" void kernel_launch(void* const* d_in, const int* in_sizes, int n_in,
                              void* d_out, int out_size, void* d_ws, size_t ws_size,
                              hipStream_t stream) {
    const float* gen   = (const float*)d_in[0];
    const float* realp = (const float*)d_in[1];
    if (n_in >= 2 && in_sizes[0] == NBATCH * DIMS * SEQ) {  // swapped order
        gen   = (const float*)d_in[1];
        realp = (const float*)d_in[0];
    }
    float*    ws  = (float*)d_ws;
    unsigned* cnt = (unsigned*)((char*)d_ws + NPAIRS * sizeof(float));
    float*    out = (float*)d_out;
    hipMemsetAsync(cnt, 0, sizeof(unsigned), stream);
    sigker_kernel<<<NPAIRS, 64, 0, stream>>>(gen, realp, ws, cnt, out);
}

// Round 12
// 85.675 us; speedup vs baseline: 1.2058x; 1.0705x over previous
//
#include <hip/hip_runtime.h>

// SignatureScoringLoss — round 12: r9 scalar PDE + compact Mm + DPP-old
// boundary injection.  (r11's v_pk_fma path regressed: pk operands need
// register pairs -> packing movs > savings. Reverted.)
//
// 544 blocks x 1 wave, one pair per block (latency regime: wall = one wave's
// cycle count; multi-pair waves regressed in r10).
//  - Mm compact 64x66 rows {[0][64 real][0]}: ramp-in m-loads clamp to the
//    zero slot; ramp-out reads feed only virtual tiles whose outputs never
//    reach a real tile (r9/r10 argument); max addr 4222 < 4224.
//  - PDE lane handoff via v_mov_dpp wave_shr:1 with old=1.0f: lane 0
//    receives the K[0][*]=1 boundary directly — no cndmask per value.
//  - Gram: lane I streams e_I(t), e_{I+1}(t) via DPP wave_shl:1 (lane 63's
//    neighbor row from a small pre-pass), dot-form with precomputed |y|^2.
// Weights calibrated r2/r3: XX 1/480 (upper triangle), XY -1/32.

#define SEQ   65
#define DIMS  8
#define MPOP  16
#define NBATCH 4
#define NPAIR_XX 120
#define NPAIRS (NBATCH*(NPAIR_XX + MPOP))   // 544
#define MST 66

__device__ __forceinline__ float wave_shr1_one(float x) { // lane I <- I-1; lane0 <- 1.0
    int xi = __builtin_bit_cast(int, x);
    int r  = __builtin_amdgcn_update_dpp(0x3f800000, xi, 0x138, 0xF, 0xF, false);
    return __builtin_bit_cast(float, r);
}
__device__ __forceinline__ float wave_shl1(float x) {     // lane I <- I+1
    int xi = __builtin_bit_cast(int, x);
    int r  = __builtin_amdgcn_update_dpp(xi, xi, 0x130, 0xF, 0xF, false);
    return __builtin_bit_cast(float, r);
}
__device__ __forceinline__ float ldm(const float* base, int idx) {
    return base[idx < 0 ? 0 : idx];   // clamp ramp-in to this row's zero slot
}

struct PS { float l0,l1,l2,l3,b0,b1,b2,b3,cn; };

__device__ __forceinline__ void pde_step(PS& s, float m) {
    float t0 = wave_shr1_one(s.b0);
    float t1 = wave_shr1_one(s.b1);
    float t2 = wave_shr1_one(s.b2);
    float t3 = wave_shr1_one(s.b3);
    float c = s.cn; s.cn = t3;
    float q12 = m * m * (1.0f / 12.0f);
    float a   = (1.0f + q12) + 0.5f * m;
    float nb  = q12 - 1.0f;
    float u0 = a*t0 + nb*c;
    float u1 = a*t1 + nb*t0;
    float u2 = a*t2 + nb*t1;
    float u3 = a*t3 + nb*t2;
    float q1 = a*s.l0 + u0;
    float q2 = a*q1 + u1;
    float q3 = a*q2 + u2;
    float q4 = a*q3 + u3;
    u0 = a*q1 + nb*s.l0; u1 = a*q2 + nb*q1; u2 = a*q3 + nb*q2; u3 = a*q4 + nb*q3;
    float r1 = a*s.l1 + u0;
    float r2 = a*r1 + u1;
    float r3 = a*r2 + u2;
    float r4 = a*r3 + u3;
    u0 = a*r1 + nb*s.l1; u1 = a*r2 + nb*r1; u2 = a*r3 + nb*r2; u3 = a*r4 + nb*r3;
    float w1 = a*s.l2 + u0;
    float w2 = a*w1 + u1;
    float w3 = a*w2 + u2;
    float w4 = a*w3 + u3;
    u0 = a*w1 + nb*s.l2; u1 = a*w2 + nb*w1; u2 = a*w3 + nb*w2; u3 = a*w4 + nb*w3;
    float v1 = a*s.l3 + u0;
    float v2 = a*v1 + u1;
    float v3 = a*v2 + u2;
    float v4 = a*v3 + u3;
    s.b0=v1; s.b1=v2; s.b2=v3; s.b3=v4;
    s.l0=q4; s.l1=r4; s.l2=w4; s.l3=v4;
}

__global__ __launch_bounds__(64, 1) void sigker_kernel(
    const float* __restrict__ gen,    // (B,16,8,65)
    const float* __restrict__ realp,  // (B,8,65)
    float* __restrict__ ws)           // 544 partials
{
    __shared__ __align__(16) float YsF[SEQ * DIMS];   // y paths [s][d]
    __shared__ float YnL[SEQ];                        // |y_t|^2
    __shared__ float R64[SEQ];                        // e-row for x_64
    __shared__ float MmL[64 * MST];                   // {[0][64 real][0]} rows

    const int tid = threadIdx.x;      // one wave
    const int I   = tid;
    const int bid = blockIdx.x;

    // ---- decode pair (unordered XX upper triangle + XY) ----
    int b, ii, jj; bool cross;
    if (bid < NBATCH * NPAIR_XX) {
        b = bid / NPAIR_XX;
        int p = bid % NPAIR_XX;
        int i = 0, acc = 0;
        while (p >= acc + (MPOP - 1 - i)) { acc += (MPOP - 1 - i); ++i; }
        ii = i; jj = i + 1 + (p - acc); cross = false;
    } else {
        int t = bid - NBATCH * NPAIR_XX;
        b = t / MPOP; ii = t % MPOP; jj = 0; cross = true;
    }

    const float* Xg = gen + (size_t)(b * MPOP + ii) * (DIMS * SEQ);
    const float* Yg = cross ? (realp + (size_t)b * (DIMS * SEQ))
                            : (gen + (size_t)(b * MPOP + jj) * (DIMS * SEQ));

    // ---- zero own-row boundary slots; stage y; x_I & x_64 to regs ----
    MmL[MST * I] = 0.f;  MmL[MST * I + 65] = 0.f;
    for (int f = tid; f < SEQ * DIMS; f += 64) {
        int d = f / SEQ, s = f - d * SEQ;
        YsF[s * DIMS + d] = Yg[f];
    }
    float x0[DIMS], x64[DIMS];
    float xn0 = 0.f, xn64 = 0.f;
    #pragma unroll
    for (int d = 0; d < DIMS; ++d) {
        x0[d]  = Xg[d * SEQ + I];   xn0  += x0[d]  * x0[d];
        x64[d] = Xg[d * SEQ + 64];  xn64 += x64[d] * x64[d];
    }
    __syncthreads();

    // ---- pre-pass: |y_t|^2 and e-row for x_64 ----
    for (int t = tid; t < SEQ; t += 64) {
        const float4* yv = (const float4*)&YsF[t * DIMS];
        float4 ya = yv[0], yb = yv[1];
        float yn  = ya.x*ya.x + ya.y*ya.y + ya.z*ya.z + ya.w*ya.w
                  + yb.x*yb.x + yb.y*yb.y + yb.z*yb.z + yb.w*yb.w;
        float dot = x64[0]*ya.x + x64[1]*ya.y + x64[2]*ya.z + x64[3]*ya.w
                  + x64[4]*yb.x + x64[5]*yb.y + x64[6]*yb.z + x64[7]*yb.w;
        YnL[t] = yn;
        R64[t] = __expf(2.f*dot - xn64 - yn);
    }
    __syncthreads();

    // ---- Gram: lane I streams e_I(t); e_{I+1}(t) via DPP shl ----
    float* mrow = &MmL[MST * I];      // real data at idx 1..64
    float ep, enp;
    {
        const float4* yv = (const float4*)&YsF[0];
        float4 ya = yv[0], yb = yv[1];
        float dot = x0[0]*ya.x + x0[1]*ya.y + x0[2]*ya.z + x0[3]*ya.w
                  + x0[4]*yb.x + x0[5]*yb.y + x0[6]*yb.z + x0[7]*yb.w;
        float e  = __expf(2.f*dot - xn0 - YnL[0]);
        float en = wave_shl1(e);
        en = (I == 63) ? R64[0] : en;
        ep = e; enp = en;
    }
    #pragma unroll 4
    for (int t = 1; t < SEQ; ++t) {
        const float4* yv = (const float4*)&YsF[t * DIMS];
        float4 ya = yv[0], yb = yv[1];
        float dot = x0[0]*ya.x + x0[1]*ya.y + x0[2]*ya.z + x0[3]*ya.w
                  + x0[4]*yb.x + x0[5]*yb.y + x0[6]*yb.z + x0[7]*yb.w;
        float e  = __expf(2.f*dot - xn0 - YnL[t]);
        float en = wave_shl1(e);
        en = (I == 63) ? R64[t] : en;
        // inc[I][t-1] = G[I+1][t] + G[I][t-1] - G[I+1][t-1] - G[I][t]
        mrow[t] = ((en - enp) + (ep - e)) * (1.0f / 16.0f);
        ep = e; enp = en;
    }
    // mrow written+read only by lane I (wave-ordered DS): no barrier.

    // ---- PDE: 127 steps, 8-deep m prefetch ----
    PS S = {1,1,1,1, 1,1,1,1, 1};
    const int ib = 1 - I;             // m idx for step D = ib + D (clamp at 0)
    float m[8];
    #pragma unroll
    for (int k = 0; k < 8; ++k) m[k] = ldm(mrow, ib + k);

    for (int g = 0; g < 14; ++g) {    // steps D = 8g .. 8g+7  (0..111)
        float n[8];
        const int D8 = g * 8 + 8;
        #pragma unroll
        for (int k = 0; k < 8; ++k) n[k] = ldm(mrow, ib + D8 + k);
        #pragma unroll
        for (int k = 0; k < 8; ++k) pde_step(S, m[k]);
        #pragma unroll
        for (int k = 0; k < 8; ++k) m[k] = n[k];
    }
    float mt[7];
    #pragma unroll
    for (int k = 0; k < 7; ++k) mt[k] = ldm(mrow, ib + 120 + k);
    #pragma unroll
    for (int k = 0; k < 8; ++k) pde_step(S, m[k]);    // D=112..119
    #pragma unroll
    for (int k = 0; k < 7; ++k) pde_step(S, mt[k]);   // D=120..126

    if (tid == 63) {
        float w = cross ? (-1.0f / 32.0f) : (1.0f / 480.0f);
        ws[bid] = w * S.b3;           // K[256][256]
    }
}

__global__ __launch_bounds__(64, 1) void sigker_reduce(
    const float* __restrict__ ws, float* __restrict__ out)
{
    const int lane = threadIdx.x;
    float s = 0.f;
    for (int k = lane; k < NPAIRS; k += 64) s += ws[k];
    #pragma unroll
    for (int off = 32; off >= 1; off >>= 1) s += __shfl_xor(s, off);
    if (lane == 0) out[0] = s;
}

extern "C" void kernel_launch(void* const* d_in, const int* in_sizes, int n_in,
                              void* d_out, int out_size, void* d_ws, size_t ws_size,
                              hipStream_t stream) {
    const float* gen   = (const float*)d_in[0];
    const float* realp = (const float*)d_in[1];
    if (n_in >= 2 && in_sizes[0] == NBATCH * DIMS * SEQ) {  // swapped order
        gen   = (const float*)d_in[1];
        realp = (const float*)d_in[0];
    }
    float* ws  = (float*)d_ws;
    float* out = (float*)d_out;
    sigker_kernel<<<NPAIRS, 64, 0, stream>>>(gen, realp, ws);
    sigker_reduce<<<1, 64, 0, stream>>>(ws, out);
}

// Round 13
// 81.688 us; speedup vs baseline: 1.2646x; 1.0488x over previous
//
#include <hip/hip_runtime.h>

// SignatureScoringLoss — round 13: precomputed (a,nb) coefficient pairs.
//
// Regime (established r4-r12): 544 single-wave blocks, wall = one wave's
// issue count (latency/issue-bound; multi-pair waves and pk-math regressed).
// This round moves the per-PDE-step coefficient math (m -> q12 -> a,nb;
// 5 VALU x 127 steps) into the 64-iteration Gram phase, storing float2
// (a, nb) per coarse cell. PDE reads one ds_read_b64 per step (pair-stride
// 67 -> odd rotation, conflict-free). Boundary pair (1,-1) == m=0 keeps the
// virtual-tile identity exact. Yn/R64 packed as float2 (one load, not two).
// A/B ping-pong prefetch buffers remove the 2-movs/step rotation.
// Weights calibrated r2/r3: XX 1/480 (upper triangle), XY -1/32.

#define SEQ   65
#define DIMS  8
#define MPOP  16
#define NBATCH 4
#define NPAIR_XX 120
#define NPAIRS (NBATCH*(NPAIR_XX + MPOP))   // 544
#define CST 67        // (a,nb) pairs per row; odd -> conflict-free b64 rotation

__device__ __forceinline__ float wave_shr1_one(float x) { // lane I <- I-1; lane0 <- 1.0
    int xi = __builtin_bit_cast(int, x);
    int r  = __builtin_amdgcn_update_dpp(0x3f800000, xi, 0x138, 0xF, 0xF, false);
    return __builtin_bit_cast(float, r);
}
__device__ __forceinline__ float wave_shl1(float x) {     // lane I <- I+1
    int xi = __builtin_bit_cast(int, x);
    int r  = __builtin_amdgcn_update_dpp(xi, xi, 0x130, 0xF, 0xF, false);
    return __builtin_bit_cast(float, r);
}
__device__ __forceinline__ float2 ldc(const float2* b, int i) {
    return b[i < 0 ? 0 : i];          // clamp ramp-in to row's boundary pair
}

struct PS { float l0,l1,l2,l3,b0,b1,b2,b3,cn; };

__device__ __forceinline__ void pde_step(PS& s, float2 co) {
    const float a  = co.x;
    const float nb = co.y;
    float t0 = wave_shr1_one(s.b0);
    float t1 = wave_shr1_one(s.b1);
    float t2 = wave_shr1_one(s.b2);
    float t3 = wave_shr1_one(s.b3);
    float c = s.cn; s.cn = t3;
    float u0 = a*t0 + nb*c;
    float u1 = a*t1 + nb*t0;
    float u2 = a*t2 + nb*t1;
    float u3 = a*t3 + nb*t2;
    float q1 = a*s.l0 + u0;
    float q2 = a*q1 + u1;
    float q3 = a*q2 + u2;
    float q4 = a*q3 + u3;
    u0 = a*q1 + nb*s.l0; u1 = a*q2 + nb*q1; u2 = a*q3 + nb*q2; u3 = a*q4 + nb*q3;
    float r1 = a*s.l1 + u0;
    float r2 = a*r1 + u1;
    float r3 = a*r2 + u2;
    float r4 = a*r3 + u3;
    u0 = a*r1 + nb*s.l1; u1 = a*r2 + nb*r1; u2 = a*r3 + nb*r2; u3 = a*r4 + nb*r3;
    float w1 = a*s.l2 + u0;
    float w2 = a*w1 + u1;
    float w3 = a*w2 + u2;
    float w4 = a*w3 + u3;
    u0 = a*w1 + nb*s.l2; u1 = a*w2 + nb*w1; u2 = a*w3 + nb*w2; u3 = a*w4 + nb*w3;
    float v1 = a*s.l3 + u0;
    float v2 = a*v1 + u1;
    float v3 = a*v2 + u2;
    float v4 = a*v3 + u3;
    s.b0=v1; s.b1=v2; s.b2=v3; s.b3=v4;
    s.l0=q4; s.l1=r4; s.l2=w4; s.l3=v4;
}

__global__ __launch_bounds__(64, 1) void sigker_kernel(
    const float* __restrict__ gen,    // (B,16,8,65)
    const float* __restrict__ realp,  // (B,8,65)
    float* __restrict__ ws)           // 544 partials
{
    __shared__ __align__(16) float YsF[SEQ * DIMS];   // y paths [s][d]
    __shared__ float2 YnR[SEQ];                       // (|y_t|^2, R64[t])
    __shared__ float2 CmL[64 * CST];                  // (a, nb) per coarse cell

    const int tid = threadIdx.x;      // one wave
    const int I   = tid;
    const int bid = blockIdx.x;

    // ---- decode pair (unordered XX upper triangle + XY) ----
    int b, ii, jj; bool cross;
    if (bid < NBATCH * NPAIR_XX) {
        b = bid / NPAIR_XX;
        int p = bid % NPAIR_XX;
        int i = 0, acc = 0;
        while (p >= acc + (MPOP - 1 - i)) { acc += (MPOP - 1 - i); ++i; }
        ii = i; jj = i + 1 + (p - acc); cross = false;
    } else {
        int t = bid - NBATCH * NPAIR_XX;
        b = t / MPOP; ii = t % MPOP; jj = 0; cross = true;
    }

    const float* Xg = gen + (size_t)(b * MPOP + ii) * (DIMS * SEQ);
    const float* Yg = cross ? (realp + (size_t)b * (DIMS * SEQ))
                            : (gen + (size_t)(b * MPOP + jj) * (DIMS * SEQ));

    // ---- boundary coefficient pair (m=0 -> a=1, nb=-1); stage y ----
    CmL[CST * I] = make_float2(1.0f, -1.0f);
    for (int f = tid; f < SEQ * DIMS; f += 64) {
        int d = f / SEQ, s = f - d * SEQ;
        YsF[s * DIMS + d] = Yg[f];
    }
    float x0[DIMS], x64[DIMS];
    float xn0 = 0.f, xn64 = 0.f;
    #pragma unroll
    for (int d = 0; d < DIMS; ++d) {
        x0[d]  = Xg[d * SEQ + I];   xn0  += x0[d]  * x0[d];
        x64[d] = Xg[d * SEQ + 64];  xn64 += x64[d] * x64[d];
    }
    __syncthreads();

    // ---- pre-pass: (|y_t|^2, e-row for x_64) ----
    for (int t = tid; t < SEQ; t += 64) {
        const float4* yv = (const float4*)&YsF[t * DIMS];
        float4 ya = yv[0], yb = yv[1];
        float yn  = ya.x*ya.x + ya.y*ya.y + ya.z*ya.z + ya.w*ya.w
                  + yb.x*yb.x + yb.y*yb.y + yb.z*yb.z + yb.w*yb.w;
        float dot = x64[0]*ya.x + x64[1]*ya.y + x64[2]*ya.z + x64[3]*ya.w
                  + x64[4]*yb.x + x64[5]*yb.y + x64[6]*yb.z + x64[7]*yb.w;
        YnR[t] = make_float2(yn, __expf(2.f*dot - xn64 - yn));
    }
    __syncthreads();

    // ---- Gram + coefficients: lane I streams e_I(t), e_{I+1} via DPP ----
    float2* crow = &CmL[CST * I];     // real pairs at idx 1..64
    float ep, enp;
    {
        const float4* yv = (const float4*)&YsF[0];
        float4 ya = yv[0], yb = yv[1];
        float dot = x0[0]*ya.x + x0[1]*ya.y + x0[2]*ya.z + x0[3]*ya.w
                  + x0[4]*yb.x + x0[5]*yb.y + x0[6]*yb.z + x0[7]*yb.w;
        float2 yr = YnR[0];
        float e  = __expf(2.f*dot - xn0 - yr.x);
        float en = wave_shl1(e);
        en = (I == 63) ? yr.y : en;
        ep = e; enp = en;
    }
    #pragma unroll 4
    for (int t = 1; t < SEQ; ++t) {
        const float4* yv = (const float4*)&YsF[t * DIMS];
        float4 ya = yv[0], yb = yv[1];
        float dot = x0[0]*ya.x + x0[1]*ya.y + x0[2]*ya.z + x0[3]*ya.w
                  + x0[4]*yb.x + x0[5]*yb.y + x0[6]*yb.z + x0[7]*yb.w;
        float2 yr = YnR[t];
        float e  = __expf(2.f*dot - xn0 - yr.x);
        float en = wave_shl1(e);
        en = (I == 63) ? yr.y : en;
        // inc[I][t-1] = G[I+1][t] + G[I][t-1] - G[I+1][t-1] - G[I][t]
        float m   = ((en - enp) + (ep - e)) * (1.0f / 16.0f);
        float q12 = m * m * (1.0f / 12.0f);
        float a   = (1.0f + q12) + 0.5f * m;
        float nb  = q12 - 1.0f;
        crow[t] = make_float2(a, nb);
        ep = e; enp = en;
    }
    // crow written+read only by lane I (wave-ordered DS): no barrier.

    // ---- PDE: 127 steps, A/B ping-pong 8-deep coefficient prefetch ----
    PS S = {1,1,1,1, 1,1,1,1, 1};
    const int ib = 1 - I;             // pair idx for step D = ib + D (clamp 0)

    float2 mA[8], mB[8];
    #pragma unroll
    for (int k = 0; k < 8; ++k) mA[k] = ldc(crow, ib + k);

    for (int g = 0; g < 7; ++g) {     // 7 x 16 = 112 steps (D = 0..111)
        const int D16 = g * 16;
        #pragma unroll
        for (int k = 0; k < 8; ++k) mB[k] = ldc(crow, ib + D16 + 8 + k);
        #pragma unroll
        for (int k = 0; k < 8; ++k) pde_step(S, mA[k]);
        #pragma unroll
        for (int k = 0; k < 8; ++k) mA[k] = ldc(crow, ib + D16 + 16 + k);
        #pragma unroll
        for (int k = 0; k < 8; ++k) pde_step(S, mB[k]);
    }
    // mA holds D=112..119; tail D=120..126
    #pragma unroll
    for (int k = 0; k < 7; ++k) mB[k] = ldc(crow, ib + 120 + k);
    #pragma unroll
    for (int k = 0; k < 8; ++k) pde_step(S, mA[k]);   // D=112..119
    #pragma unroll
    for (int k = 0; k < 7; ++k) pde_step(S, mB[k]);   // D=120..126

    if (tid == 63) {
        float w = cross ? (-1.0f / 32.0f) : (1.0f / 480.0f);
        ws[bid] = w * S.b3;           // K[256][256]
    }
}

__global__ __launch_bounds__(64, 1) void sigker_reduce(
    const float* __restrict__ ws, float* __restrict__ out)
{
    const int lane = threadIdx.x;
    float s = 0.f;
    for (int k = lane; k < NPAIRS; k += 64) s += ws[k];
    #pragma unroll
    for (int off = 32; off >= 1; off >>= 1) s += __shfl_xor(s, off);
    if (lane == 0) out[0] = s;
}

extern "C" void kernel_launch(void* const* d_in, const int* in_sizes, int n_in,
                              void* d_out, int out_size, void* d_ws, size_t ws_size,
                              hipStream_t stream) {
    const float* gen   = (const float*)d_in[0];
    const float* realp = (const float*)d_in[1];
    if (n_in >= 2 && in_sizes[0] == NBATCH * DIMS * SEQ) {  // swapped order
        gen   = (const float*)d_in[1];
        realp = (const float*)d_in[0];
    }
    float* ws  = (float*)d_ws;
    float* out = (float*)d_out;
    sigker_kernel<<<NPAIRS, 64, 0, stream>>>(gen, realp, ws);
    sigker_reduce<<<1, 64, 0, stream>>>(ws, out);
}

// Round 14
// 81.324 us; speedup vs baseline: 1.2703x; 1.0045x over previous
//
#include <hip/hip_runtime.h>

// SignatureScoringLoss — round 14: r13 + full Gram unroll + early coefficient
// prefetch. Regime (r4-r13): 544 single-wave blocks; wall = one wave's issue/
// latency count. PDE per-step floor = 32 FMA + 4 DPP + 1 ds_read_b64 + ~2.
//  - Mm stored as (a, nb) float2 coefficient pairs (computed in Gram phase);
//    boundary pair (1,-1) == m=0 keeps the virtual-tile identity exact.
//  - PDE lane handoff via v_mov_dpp wave_shr:1 with old=1.0 (K[0][*]=1 free).
//  - Gram fully unrolled; first 8 coefficient pairs loaded mid-Gram (own-row
//    DS, available after t=8) so the PDE starts without an LDS stall.
// Weights calibrated r2/r3: XX 1/480 (upper triangle), XY -1/32.

#define SEQ   65
#define DIMS  8
#define MPOP  16
#define NBATCH 4
#define NPAIR_XX 120
#define NPAIRS (NBATCH*(NPAIR_XX + MPOP))   // 544
#define CST 67        // (a,nb) pairs per row; odd stride -> conflict-free b64

__device__ __forceinline__ float wave_shr1_one(float x) { // lane I <- I-1; lane0 <- 1.0
    int xi = __builtin_bit_cast(int, x);
    int r  = __builtin_amdgcn_update_dpp(0x3f800000, xi, 0x138, 0xF, 0xF, false);
    return __builtin_bit_cast(float, r);
}
__device__ __forceinline__ float wave_shl1(float x) {     // lane I <- I+1
    int xi = __builtin_bit_cast(int, x);
    int r  = __builtin_amdgcn_update_dpp(xi, xi, 0x130, 0xF, 0xF, false);
    return __builtin_bit_cast(float, r);
}
__device__ __forceinline__ float2 ldc(const float2* b, int i) {
    return b[i < 0 ? 0 : i];          // clamp ramp-in to row's boundary pair
}

struct PS { float l0,l1,l2,l3,b0,b1,b2,b3,cn; };

__device__ __forceinline__ void pde_step(PS& s, float2 co) {
    const float a  = co.x;
    const float nb = co.y;
    float t0 = wave_shr1_one(s.b0);
    float t1 = wave_shr1_one(s.b1);
    float t2 = wave_shr1_one(s.b2);
    float t3 = wave_shr1_one(s.b3);
    float c = s.cn; s.cn = t3;
    float u0 = a*t0 + nb*c;
    float u1 = a*t1 + nb*t0;
    float u2 = a*t2 + nb*t1;
    float u3 = a*t3 + nb*t2;
    float q1 = a*s.l0 + u0;
    float q2 = a*q1 + u1;
    float q3 = a*q2 + u2;
    float q4 = a*q3 + u3;
    u0 = a*q1 + nb*s.l0; u1 = a*q2 + nb*q1; u2 = a*q3 + nb*q2; u3 = a*q4 + nb*q3;
    float r1 = a*s.l1 + u0;
    float r2 = a*r1 + u1;
    float r3 = a*r2 + u2;
    float r4 = a*r3 + u3;
    u0 = a*r1 + nb*s.l1; u1 = a*r2 + nb*r1; u2 = a*r3 + nb*r2; u3 = a*r4 + nb*r3;
    float w1 = a*s.l2 + u0;
    float w2 = a*w1 + u1;
    float w3 = a*w2 + u2;
    float w4 = a*w3 + u3;
    u0 = a*w1 + nb*s.l2; u1 = a*w2 + nb*w1; u2 = a*w3 + nb*w2; u3 = a*w4 + nb*w3;
    float v1 = a*s.l3 + u0;
    float v2 = a*v1 + u1;
    float v3 = a*v2 + u2;
    float v4 = a*v3 + u3;
    s.b0=v1; s.b1=v2; s.b2=v3; s.b3=v4;
    s.l0=q4; s.l1=r4; s.l2=w4; s.l3=v4;
}

__global__ __launch_bounds__(64, 1) void sigker_kernel(
    const float* __restrict__ gen,    // (B,16,8,65)
    const float* __restrict__ realp,  // (B,8,65)
    float* __restrict__ ws)           // 544 partials
{
    __shared__ __align__(16) float YsF[SEQ * DIMS];   // y paths [s][d]
    __shared__ float2 YnR[SEQ];                       // (|y_t|^2, R64[t])
    __shared__ float2 CmL[64 * CST];                  // (a, nb) per coarse cell

    const int tid = threadIdx.x;      // one wave
    const int I   = tid;
    const int bid = blockIdx.x;

    // ---- decode pair (unordered XX upper triangle + XY) ----
    int b, ii, jj; bool cross;
    if (bid < NBATCH * NPAIR_XX) {
        b = bid / NPAIR_XX;
        int p = bid % NPAIR_XX;
        int i = 0, acc = 0;
        while (p >= acc + (MPOP - 1 - i)) { acc += (MPOP - 1 - i); ++i; }
        ii = i; jj = i + 1 + (p - acc); cross = false;
    } else {
        int t = bid - NBATCH * NPAIR_XX;
        b = t / MPOP; ii = t % MPOP; jj = 0; cross = true;
    }

    const float* Xg = gen + (size_t)(b * MPOP + ii) * (DIMS * SEQ);
    const float* Yg = cross ? (realp + (size_t)b * (DIMS * SEQ))
                            : (gen + (size_t)(b * MPOP + jj) * (DIMS * SEQ));

    // ---- global loads first (overlap latency with LDS setup) ----
    float x0[DIMS], x64[DIMS];
    #pragma unroll
    for (int d = 0; d < DIMS; ++d) {
        x0[d]  = Xg[d * SEQ + I];
        x64[d] = Xg[d * SEQ + 64];    // uniform addr -> broadcast
    }
    CmL[CST * I] = make_float2(1.0f, -1.0f);   // boundary pair (m=0)
    for (int f = tid; f < SEQ * DIMS; f += 64) {
        int d = f / SEQ, s = f - d * SEQ;
        YsF[s * DIMS + d] = Yg[f];
    }
    float xn0 = 0.f, xn64 = 0.f;
    #pragma unroll
    for (int d = 0; d < DIMS; ++d) {
        xn0  += x0[d]  * x0[d];
        xn64 += x64[d] * x64[d];
    }
    __syncthreads();

    // ---- pre-pass: (|y_t|^2, e-row for x_64) ----
    for (int t = tid; t < SEQ; t += 64) {
        const float4* yv = (const float4*)&YsF[t * DIMS];
        float4 ya = yv[0], yb = yv[1];
        float yn  = ya.x*ya.x + ya.y*ya.y + ya.z*ya.z + ya.w*ya.w
                  + yb.x*yb.x + yb.y*yb.y + yb.z*yb.z + yb.w*yb.w;
        float dot = x64[0]*ya.x + x64[1]*ya.y + x64[2]*ya.z + x64[3]*ya.w
                  + x64[4]*yb.x + x64[5]*yb.y + x64[6]*yb.z + x64[7]*yb.w;
        YnR[t] = make_float2(yn, __expf(2.f*dot - xn64 - yn));
    }
    __syncthreads();

    // ---- Gram + coefficients (fully unrolled), early mA prefetch ----
    float2* crow = &CmL[CST * I];     // real pairs at idx 1..64
    const int ib = 1 - I;             // PDE pair idx for step D = ib + D
    float2 mA[8], mB[8];
    float ep, enp;
    {
        const float4* yv = (const float4*)&YsF[0];
        float4 ya = yv[0], yb = yv[1];
        float dot = x0[0]*ya.x + x0[1]*ya.y + x0[2]*ya.z + x0[3]*ya.w
                  + x0[4]*yb.x + x0[5]*yb.y + x0[6]*yb.z + x0[7]*yb.w;
        float2 yr = YnR[0];
        float e  = __expf(2.f*dot - xn0 - yr.x);
        float en = wave_shl1(e);
        en = (I == 63) ? yr.y : en;
        ep = e; enp = en;
    }
    #pragma unroll
    for (int t = 1; t < SEQ; ++t) {
        const float4* yv = (const float4*)&YsF[t * DIMS];
        float4 ya = yv[0], yb = yv[1];
        float dot = x0[0]*ya.x + x0[1]*ya.y + x0[2]*ya.z + x0[3]*ya.w
                  + x0[4]*yb.x + x0[5]*yb.y + x0[6]*yb.z + x0[7]*yb.w;
        float2 yr = YnR[t];
        float e  = __expf(2.f*dot - xn0 - yr.x);
        float en = wave_shl1(e);
        en = (I == 63) ? yr.y : en;
        // inc[I][t-1] = G[I+1][t] + G[I][t-1] - G[I+1][t-1] - G[I][t]
        float m   = ((en - enp) + (ep - e)) * (1.0f / 16.0f);
        float q12 = m * m * (1.0f / 12.0f);
        float a   = (1.0f + q12) + 0.5f * m;
        float nb  = q12 - 1.0f;
        crow[t] = make_float2(a, nb);
        ep = e; enp = en;
        if (t == 8) {
            // lane I's PDE warm-up pairs are crow[clamp(ib..ib+7)], max idx 8:
            // all written by now (own-row, wave-ordered DS). Load early so
            // their latency hides under the remaining 56 Gram iterations.
            #pragma unroll
            for (int k = 0; k < 8; ++k) mA[k] = ldc(crow, ib + k);
        }
    }
    // crow written+read only by lane I (wave-ordered DS): no barrier.

    // ---- PDE: 127 steps, A/B ping-pong 8-deep coefficient prefetch ----
    PS S = {1,1,1,1, 1,1,1,1, 1};

    for (int g = 0; g < 7; ++g) {     // 7 x 16 = 112 steps (D = 0..111)
        const int D16 = g * 16;
        #pragma unroll
        for (int k = 0; k < 8; ++k) mB[k] = ldc(crow, ib + D16 + 8 + k);
        #pragma unroll
        for (int k = 0; k < 8; ++k) pde_step(S, mA[k]);
        #pragma unroll
        for (int k = 0; k < 8; ++k) mA[k] = ldc(crow, ib + D16 + 16 + k);
        #pragma unroll
        for (int k = 0; k < 8; ++k) pde_step(S, mB[k]);
    }
    // mA holds D=112..119; tail D=120..126
    #pragma unroll
    for (int k = 0; k < 7; ++k) mB[k] = ldc(crow, ib + 120 + k);
    #pragma unroll
    for (int k = 0; k < 8; ++k) pde_step(S, mA[k]);   // D=112..119
    #pragma unroll
    for (int k = 0; k < 7; ++k) pde_step(S, mB[k]);   // D=120..126

    if (tid == 63) {
        float w = cross ? (-1.0f / 32.0f) : (1.0f / 480.0f);
        ws[bid] = w * S.b3;           // K[256][256]
    }
}

__global__ __launch_bounds__(64, 1) void sigker_reduce(
    const float* __restrict__ ws, float* __restrict__ out)
{
    const int lane = threadIdx.x;
    float s = 0.f;
    for (int k = lane; k < NPAIRS; k += 64) s += ws[k];
    #pragma unroll
    for (int off = 32; off >= 1; off >>= 1) s += __shfl_xor(s, off);
    if (lane == 0) out[0] = s;
}

extern "C" void kernel_launch(void* const* d_in, const int* in_sizes, int n_in,
                              void* d_out, int out_size, void* d_ws, size_t ws_size,
                              hipStream_t stream) {
    const float* gen   = (const float*)d_in[0];
    const float* realp = (const float*)d_in[1];
    if (n_in >= 2 && in_sizes[0] == NBATCH * DIMS * SEQ) {  // swapped order
        gen   = (const float*)d_in[1];
        realp = (const float*)d_in[0];
    }
    float* ws  = (float*)d_ws;
    float* out = (float*)d_out;
    sigker_kernel<<<NPAIRS, 64, 0, stream>>>(gen, realp, ws);
    sigker_reduce<<<1, 64, 0, stream>>>(ws, out);
}